// Round 2
// baseline (451.081 us; speedup 1.0000x reference)
//
#include <hip/hip_runtime.h>
#include <hip/hip_bf16.h>

#define N_NODES 131072
#define B_SEG   2048
#define F_DIM   200
#define K_DIM   608      // 400 (q_star) + 200 (h), K padded to 19*32
#define MAXSEG  128

typedef __attribute__((ext_vector_type(8))) short bf16x8;
typedef __attribute__((ext_vector_type(4))) float f32x4;

__device__ __forceinline__ float b2f(unsigned short u) {
  union { unsigned int i; float f; } v; v.i = ((unsigned int)u) << 16; return v.f;
}
__device__ __forceinline__ unsigned short f2bu(float f) {
  __hip_bfloat16 h = __float2bfloat16(f);
  return *reinterpret_cast<unsigned short*>(&h);
}
__device__ __forceinline__ int lower_bound(const int* __restrict__ a, int n, int v) {
  int lo = 0, hi = n;
  while (lo < hi) { int mid = (lo + hi) >> 1; if (a[mid] < v) lo = mid + 1; else hi = mid; }
  return lo;
}
__device__ __forceinline__ float sigmoidf_(float x) { return 1.f / (1.f + __expf(-x)); }

// ---- convert x (f32) -> xb (bf16), flat ----
__global__ __launch_bounds__(256) void convert_x_kernel(
    const float* __restrict__ x, unsigned short* __restrict__ xb) {
  int i = blockIdx.x * 256 + threadIdx.x;   // float4 index; grid covers exactly N*F/4
  float4 v = ((const float4*)x)[i];
  ushort4 o;
  o.x = f2bu(v.x); o.y = f2bu(v.y); o.z = f2bu(v.z); o.w = f2bu(v.w);
  ((ushort4*)xb)[i] = o;
}

// ---- pack W_ih | W_hh (f32) into Wc[800][608] bf16, zero-padded K 600..607 ----
__global__ __launch_bounds__(256) void pack_w_kernel(
    const float* __restrict__ Wih, const float* __restrict__ Whh,
    unsigned short* __restrict__ Wc) {
  int idx = blockIdx.x * 256 + threadIdx.x;
  if (idx >= 800 * K_DIM) return;
  int row = idx / K_DIM, k = idx - row * K_DIM;
  float v = 0.f;
  if (k < 400)      v = Wih[row * 400 + k];
  else if (k < 600) v = Whh[row * 200 + (k - 400)];
  Wc[idx] = f2bu(v);
}

// ---- init: h0 = segment_sum(cos*x), c=0, A=[q_star_in | h0 | pad0] ----
__global__ __launch_bounds__(256) void init_kernel(
    const float* __restrict__ xf, const unsigned short* __restrict__ xb,
    const int* __restrict__ batch, const float* __restrict__ cosc,
    const float* __restrict__ qs0, float* __restrict__ h, float* __restrict__ c,
    unsigned short* __restrict__ A) {
  __shared__ __align__(16) unsigned short xs[MAXSEG * F_DIM];
  int b = blockIdx.x, tid = threadIdx.x;
  int start = lower_bound(batch, N_NODES, b);
  int end   = lower_bound(batch, N_NODES, b + 1);
  int n = end - start;
  bool staged = (n <= MAXSEG) && (xb != nullptr);
  if (staged) {
    const uint2* src = (const uint2*)(xb + (size_t)start * F_DIM);
    uint2* dst = (uint2*)xs;
    int cnt = n * (F_DIM / 4);
    for (int i = tid; i < cnt; i += 256) dst[i] = src[i];
  }
  __syncthreads();
  if (tid < F_DIM) {
    float acc = 0.f;
    if (staged) {
      for (int i = 0; i < n; i++) acc += cosc[start + i] * b2f(xs[i * F_DIM + tid]);
    } else {
      for (int i = 0; i < n; i++)
        acc += cosc[start + i] * xf[(size_t)(start + i) * F_DIM + tid];
    }
    h[(size_t)b * F_DIM + tid] = acc;
    c[(size_t)b * F_DIM + tid] = 0.f;
    A[(size_t)b * K_DIM + 400 + tid] = f2bu(acc);
  }
  for (int j = tid; j < 400; j += 256)
    A[(size_t)b * K_DIM + j] = f2bu(qs0[(size_t)b * 400 + j]);
  if (tid < 8) A[(size_t)b * K_DIM + 600 + tid] = 0;
}

// ---- gates GEMM: gates[2048,800] = A[2048,608] x Wc[800,608]^T, bf16 MFMA ----
__global__ __launch_bounds__(256) void gemm_gates(
    const unsigned short* __restrict__ A, const unsigned short* __restrict__ W,
    float* __restrict__ gates) {
  __shared__ __align__(16) unsigned short As[64 * 32];
  __shared__ __align__(16) unsigned short Ws[80 * 32];
  int tid = threadIdx.x;
  int bm = blockIdx.x * 64, bn = blockIdx.y * 80;
  int wave = tid >> 6, lane = tid & 63;
  int quad = lane >> 4, col = lane & 15;
  f32x4 acc[5];
#pragma unroll
  for (int t = 0; t < 5; t++) acc[t] = (f32x4){0.f, 0.f, 0.f, 0.f};
  int arow = tid >> 2, akc = tid & 3;
  for (int k0 = 0; k0 < K_DIM; k0 += 32) {
    *(uint4*)(As + arow * 32 + akc * 8) =
        *(const uint4*)(A + (size_t)(bm + arow) * K_DIM + k0 + akc * 8);
    for (int idx = tid; idx < 320; idx += 256) {
      int wrow = idx >> 2, wkc = idx & 3;
      *(uint4*)(Ws + wrow * 32 + wkc * 8) =
          *(const uint4*)(W + (size_t)(bn + wrow) * K_DIM + k0 + wkc * 8);
    }
    __syncthreads();
    bf16x8 af = *(const bf16x8*)(As + (wave * 16 + col) * 32 + quad * 8);
#pragma unroll
    for (int t = 0; t < 5; t++) {
      bf16x8 bfr = *(const bf16x8*)(Ws + (t * 16 + col) * 32 + quad * 8);
      acc[t] = __builtin_amdgcn_mfma_f32_16x16x32_bf16(af, bfr, acc[t], 0, 0, 0);
    }
    __syncthreads();
  }
#pragma unroll
  for (int t = 0; t < 5; t++) {
#pragma unroll
    for (int r = 0; r < 4; r++) {
      int gm = bm + wave * 16 + quad * 4 + r;
      int gn = bn + t * 16 + col;
      gates[(size_t)gm * 800 + gn] = acc[t][r];
    }
  }
}

// ---- pointwise LSTM cell; writes h (f32 + into A cols 0..199 and 400..599) ----
__global__ __launch_bounds__(256) void lstm_pointwise(
    const float* __restrict__ gates, const float* __restrict__ bih,
    const float* __restrict__ bhh, float* __restrict__ h,
    float* __restrict__ c, unsigned short* __restrict__ A) {
  int idx = blockIdx.x * 256 + threadIdx.x;
  if (idx >= B_SEG * F_DIM) return;
  int b = idx / F_DIM, f = idx - b * F_DIM;
  const float* g = gates + (size_t)b * 800;
  float gi = g[f]       + bih[f]       + bhh[f];
  float gf = g[200 + f] + bih[200 + f] + bhh[200 + f];
  float gg = g[400 + f] + bih[400 + f] + bhh[400 + f];
  float go = g[600 + f] + bih[600 + f] + bhh[600 + f];
  float cn = sigmoidf_(gf) * c[idx] + sigmoidf_(gi) * tanhf(gg);
  float hn = sigmoidf_(go) * tanhf(cn);
  c[idx] = cn;
  h[idx] = hn;
  unsigned short hb = f2bu(hn);
  A[(size_t)b * K_DIM + f]       = hb;
  A[(size_t)b * K_DIM + 400 + f] = hb;
}

// ---- per-segment attention: e = x.q, softmax, r = a.x ----
__global__ __launch_bounds__(256) void attn_kernel(
    const float* __restrict__ xf, const unsigned short* __restrict__ xb,
    const int* __restrict__ batch, const float* __restrict__ h,
    float* __restrict__ scratch, unsigned short* __restrict__ A,
    float* __restrict__ out, int final_step) {
  __shared__ __align__(16) unsigned short xs[MAXSEG * F_DIM];
  __shared__ float e_s[MAXSEG];
  __shared__ float q_s[F_DIM];
  __shared__ float red[8];
  int b = blockIdx.x, tid = threadIdx.x;
  int start = lower_bound(batch, N_NODES, b);
  int end   = lower_bound(batch, N_NODES, b + 1);
  int n = end - start;
  if (tid < F_DIM) q_s[tid] = h[(size_t)b * F_DIM + tid];
  bool staged = (n <= MAXSEG) && (xb != nullptr);
  float* e_arr = staged ? e_s : (scratch + (size_t)b * 800);
  if (staged) {
    const uint2* src = (const uint2*)(xb + (size_t)start * F_DIM);
    uint2* dst = (uint2*)xs;
    int cnt = n * (F_DIM / 4);
    for (int i = tid; i < cnt; i += 256) dst[i] = src[i];
  }
  __syncthreads();
  int wave = tid >> 6, lane = tid & 63;
  // e-pass: one row per wave, lanes 0..49 cover 200 features x4
  for (int r = wave; r < n; r += 4) {
    float p = 0.f;
    if (lane < 50) {
      if (staged) {
        ushort4 v = *(const ushort4*)(xs + r * F_DIM + 4 * lane);
        p = q_s[4 * lane]     * b2f(v.x) + q_s[4 * lane + 1] * b2f(v.y)
          + q_s[4 * lane + 2] * b2f(v.z) + q_s[4 * lane + 3] * b2f(v.w);
      } else {
        float4 v = *(const float4*)(xf + (size_t)(start + r) * F_DIM + 4 * lane);
        p = q_s[4 * lane]     * v.x + q_s[4 * lane + 1] * v.y
          + q_s[4 * lane + 2] * v.z + q_s[4 * lane + 3] * v.w;
      }
    }
#pragma unroll
    for (int off = 32; off; off >>= 1) p += __shfl_down(p, off);
    if (lane == 0) e_arr[r] = p;
  }
  __syncthreads();
  // segment max
  float pm = -3.4e38f;
  for (int i = tid; i < n; i += 256) pm = fmaxf(pm, e_arr[i]);
#pragma unroll
  for (int off = 32; off; off >>= 1) pm = fmaxf(pm, __shfl_down(pm, off));
  if (lane == 0) red[wave] = pm;
  __syncthreads();
  float m = fmaxf(fmaxf(red[0], red[1]), fmaxf(red[2], red[3]));
  // exp + denom
  float ps = 0.f;
  for (int i = tid; i < n; i += 256) {
    float ex = __expf(e_arr[i] - m);
    e_arr[i] = ex;
    ps += ex;
  }
#pragma unroll
  for (int off = 32; off; off >>= 1) ps += __shfl_down(ps, off);
  if (lane == 0) red[4 + wave] = ps;
  __syncthreads();
  float denom = red[4] + red[5] + red[6] + red[7];
  float inv = (denom > 0.f) ? 1.f / denom : 0.f;
  // r-pass: feature-parallel weighted sum, scale by 1/denom at the end
  if (tid < F_DIM) {
    float acc = 0.f;
    if (staged) {
      for (int i = 0; i < n; i++) acc += e_arr[i] * b2f(xs[i * F_DIM + tid]);
    } else {
      for (int i = 0; i < n; i++)
        acc += e_arr[i] * xf[(size_t)(start + i) * F_DIM + tid];
    }
    float rv = acc * inv;
    if (!final_step) {
      A[(size_t)b * K_DIM + 200 + tid] = f2bu(rv);
    } else {
      out[(size_t)b * 400 + 200 + tid] = rv;
      out[(size_t)b * 400 + tid]       = q_s[tid];
    }
  }
}

extern "C" void kernel_launch(void* const* d_in, const int* in_sizes, int n_in,
                              void* d_out, int out_size, void* d_ws, size_t ws_size,
                              hipStream_t stream) {
  const float* x    = (const float*)d_in[0];
  const int*   batch= (const int*)d_in[1];
  const float* cosc = (const float*)d_in[2];
  const float* qs0  = (const float*)d_in[3];
  const float* Wih  = (const float*)d_in[4];
  const float* Whh  = (const float*)d_in[5];
  const float* bih  = (const float*)d_in[6];
  const float* bhh  = (const float*)d_in[7];
  char* ws = (char*)d_ws;
  // primary ws layout (bytes, all 16B aligned):
  //   xb    : 0          .. 52,428,800   (131072*200 bf16)
  //   A     : +0         ..  2,490,368   (2048*608 bf16)
  //   Wc    : +2,490,368 ..    972,800   (800*608 bf16)
  //   gates : +3,463,168 ..  6,553,600   (2048*800 f32)
  //   h     : +10,016,768..  1,638,400   (2048*200 f32)
  //   c     : +11,655,168..  1,638,400   (2048*200 f32)
  const size_t XB_BYTES = 52428800;
  const size_t TAIL_BYTES = 13293568;
  bool use_xb = (ws_size >= XB_BYTES + TAIL_BYTES);
  size_t off = use_xb ? XB_BYTES : 0;
  unsigned short* xb = use_xb ? (unsigned short*)ws : nullptr;
  unsigned short* A  = (unsigned short*)(ws + off);
  unsigned short* Wc = (unsigned short*)(ws + off + 2490368);
  float* gates       = (float*)(ws + off + 3463168);
  float* h           = (float*)(ws + off + 10016768);
  float* c           = (float*)(ws + off + 11655168);
  float* outp        = (float*)d_out;

  if (use_xb)
    convert_x_kernel<<<(N_NODES * F_DIM / 4) / 256, 256, 0, stream>>>(x, xb);
  pack_w_kernel<<<(800 * K_DIM + 255) / 256, 256, 0, stream>>>(Wih, Whh, Wc);
  init_kernel<<<B_SEG, 256, 0, stream>>>(x, xb, batch, cosc, qs0, h, c, A);
  for (int s = 0; s < 3; s++) {
    gemm_gates<<<dim3(32, 10), 256, 0, stream>>>(A, Wc, gates);
    lstm_pointwise<<<(B_SEG * F_DIM + 255) / 256, 256, 0, stream>>>(gates, bih, bhh, h, c, A);
    attn_kernel<<<B_SEG, 256, 0, stream>>>(x, xb, batch, h, gates, A, outp, s == 2);
  }
}

// Round 4
// 350.100 us; speedup vs baseline: 1.2884x; 1.2884x over previous
//
#include <hip/hip_runtime.h>
#include <hip/hip_bf16.h>

#define N_NODES 131072
#define B_SEG   2048
#define F_DIM   200
#define K_DIM   608      // 400 (q_star) + 200 (h) + 8 zero pad = 19*32
#define W_ROWS  832      // 800 gate rows padded to 13*64
#define MAXSEG  128

typedef __attribute__((ext_vector_type(8))) short bf16x8;
typedef __attribute__((ext_vector_type(4))) float f32x4;

__device__ __forceinline__ float b2f(unsigned short u) {
  union { unsigned int i; float f; } v; v.i = ((unsigned int)u) << 16; return v.f;
}
__device__ __forceinline__ unsigned short f2bu(float f) {
  __hip_bfloat16 h = __float2bfloat16(f);
  return *reinterpret_cast<unsigned short*>(&h);
}
__device__ __forceinline__ float sigmoidf_(float x) { return 1.f / (1.f + __expf(-x)); }

// ---- setup: pack Wc[832][608] bf16 (zero-padded), seg offsets, bias sum ----
__global__ __launch_bounds__(256) void setup_kernel(
    const float* __restrict__ Wih, const float* __restrict__ Whh,
    const float* __restrict__ bih, const float* __restrict__ bhh,
    const int* __restrict__ batch, unsigned short* __restrict__ Wc,
    float* __restrict__ bsum, int* __restrict__ seg_off) {
  int bid = blockIdx.x, tid = threadIdx.x;
  if (bid < 1976) {                       // 832*608/256 == 1976 exactly
    int idx = bid * 256 + tid;
    int row = idx / K_DIM, k = idx - row * K_DIM;
    float v = 0.f;
    if (row < 800) {
      if (k < 400)      v = Wih[row * 400 + k];
      else if (k < 600) v = Whh[row * 200 + (k - 400)];
    }
    Wc[idx] = f2bu(v);
  } else if (bid < 1976 + 512) {          // 131072/256 == 512
    int i = (bid - 1976) * 256 + tid;
    int v  = batch[i];
    int pv = (i == 0) ? -1 : batch[i - 1];
    for (int b = pv + 1; b <= v; b++) seg_off[b] = i;
  } else {
    int idx = (bid - 2488) * 256 + tid;
    if (idx < 800) bsum[idx] = bih[idx] + bhh[idx];
    else if (idx == 800) {                // trailing (possibly empty) segments
      int last = batch[N_NODES - 1];
      for (int b = last + 1; b <= B_SEG; b++) seg_off[b] = N_NODES;
    }
  }
}

// ---- init: xb = bf16(x); A = [qs0 | h0 | 0]; h0 = segment_sum(cos*x) ----
__global__ __launch_bounds__(256) void init_kernel(
    const float* __restrict__ xf, const int* __restrict__ seg_off,
    const float* __restrict__ cosc, const float* __restrict__ qs0,
    unsigned short* __restrict__ xb, unsigned short* __restrict__ A) {
  __shared__ __align__(16) unsigned short xs[MAXSEG * F_DIM];
  int b = blockIdx.x, tid = threadIdx.x;
  int start = seg_off[b], end = seg_off[b + 1];
  int n = end - start;
  unsigned short* Arow = A + (size_t)b * K_DIM;
  bool staged = (n <= MAXSEG);
  if (staged) {
    int cnt = n * 50;                     // float4 (16B) chunks: n*200 floats
    const float4* src = (const float4*)(xf + (size_t)start * F_DIM);
    ushort4* ldst = (ushort4*)xs;         // ushort4 = 8B, index i covers n*200 shorts
    ushort4* gdst = (ushort4*)(xb + (size_t)start * F_DIM);
    for (int i = tid; i < cnt; i += 256) {
      float4 v = src[i];
      ushort4 o; o.x = f2bu(v.x); o.y = f2bu(v.y); o.z = f2bu(v.z); o.w = f2bu(v.w);
      ldst[i] = o; gdst[i] = o;
    }
  }
  for (int j = tid; j < 400; j += 256)
    Arow[j] = f2bu(qs0[(size_t)b * 400 + j]);
  if (tid < 8) Arow[600 + tid] = 0;
  __syncthreads();
  if (tid < F_DIM) {
    float acc = 0.f;
    if (staged) {
      for (int i = 0; i < n; i++) acc += cosc[start + i] * b2f(xs[i * F_DIM + tid]);
    } else {
      for (int i = 0; i < n; i++)
        acc += cosc[start + i] * xf[(size_t)(start + i) * F_DIM + tid];
    }
    Arow[400 + tid] = f2bu(acc);
  }
}

// ---- gates GEMM, barrier-free: gates[2048,800] = A[2048,608] x Wc^T ----
__global__ __launch_bounds__(256) void gemm_gates(
    const unsigned short* __restrict__ A, const unsigned short* __restrict__ W,
    float* __restrict__ gates) {
  int tid = threadIdx.x;
  int bm = blockIdx.x * 64, bn = blockIdx.y * 64;
  int wave = tid >> 6, lane = tid & 63;
  int quad = lane >> 4, col = lane & 15;
  f32x4 acc[4];
#pragma unroll
  for (int t = 0; t < 4; t++) acc[t] = (f32x4){0.f, 0.f, 0.f, 0.f};
  const unsigned short* Ap = A + (size_t)(bm + wave * 16 + col) * K_DIM + quad * 8;
  const unsigned short* Wp = W + (size_t)(bn + col) * K_DIM + quad * 8;
#pragma unroll
  for (int k0 = 0; k0 < K_DIM; k0 += 32) {
    bf16x8 af = *(const bf16x8*)(Ap + k0);
#pragma unroll
    for (int t = 0; t < 4; t++) {
      bf16x8 bfr = *(const bf16x8*)(Wp + (size_t)t * 16 * K_DIM + k0);
      acc[t] = __builtin_amdgcn_mfma_f32_16x16x32_bf16(af, bfr, acc[t], 0, 0, 0);
    }
  }
#pragma unroll
  for (int t = 0; t < 4; t++) {
    int gn = bn + t * 16 + col;
    if (gn < 800) {
#pragma unroll
      for (int r = 0; r < 4; r++) {
        int gm = bm + wave * 16 + quad * 4 + r;
        gates[(size_t)gm * 800 + gn] = acc[t][r];
      }
    }
  }
}

// ---- fused LSTM cell + per-segment attention ----
__global__ __launch_bounds__(256) void attn_fused(
    const float* __restrict__ xf, const unsigned short* __restrict__ xb,
    const int* __restrict__ seg_off, const float* __restrict__ gates,
    const float* __restrict__ bsum, float* __restrict__ cvec,
    float* __restrict__ esc, unsigned short* __restrict__ A,
    float* __restrict__ out, int step) {
  __shared__ __align__(16) unsigned short xs[MAXSEG * F_DIM];
  __shared__ float e_s[MAXSEG];
  __shared__ float q_s[F_DIM];
  __shared__ float red[8];
  int b = blockIdx.x, tid = threadIdx.x;
  int start = seg_off[b], end = seg_off[b + 1];
  int n = end - start;
  bool staged = (n <= MAXSEG);
  float* e_arr = staged ? e_s : (esc + start);
  unsigned short* Arow = A + (size_t)b * K_DIM;
  // stage x tile (bf16) first so the loads overlap the cell math
  if (staged) {
    int cnt = n * 25;                     // uint4 (16B) chunks: n*400 bytes total
    const uint4* src = (const uint4*)(xb + (size_t)start * F_DIM);
    uint4* dst = (uint4*)xs;
    for (int i = tid; i < cnt; i += 256) dst[i] = src[i];
  }
  // LSTM cell for this segment's 200 features
  if (tid < F_DIM) {
    int f = tid;
    const float* g = gates + (size_t)b * 800;
    float gi = g[f]       + bsum[f];
    float gf = g[200 + f] + bsum[200 + f];
    float gg = g[400 + f] + bsum[400 + f];
    float go = g[600 + f] + bsum[600 + f];
    float cp = (step > 0) ? cvec[(size_t)b * F_DIM + f] : 0.f;
    float cn = sigmoidf_(gf) * cp + sigmoidf_(gi) * tanhf(gg);
    float hn = sigmoidf_(go) * tanhf(cn);
    cvec[(size_t)b * F_DIM + f] = cn;
    q_s[f] = hn;
    if (step < 2) {
      unsigned short hb = f2bu(hn);
      Arow[f] = hb;                       // q part of next q_star
      Arow[400 + f] = hb;                 // hidden for next cell
    }
  }
  __syncthreads();
  int wave = tid >> 6, lane = tid & 63;
  // e-pass: one row per wave, lanes 0..49 cover 200 features x4
  for (int r = wave; r < n; r += 4) {
    float p = 0.f;
    if (lane < 50) {
      if (staged) {
        ushort4 v = *(const ushort4*)(xs + r * F_DIM + 4 * lane);
        p = q_s[4 * lane]     * b2f(v.x) + q_s[4 * lane + 1] * b2f(v.y)
          + q_s[4 * lane + 2] * b2f(v.z) + q_s[4 * lane + 3] * b2f(v.w);
      } else {
        float4 v = *(const float4*)(xf + (size_t)(start + r) * F_DIM + 4 * lane);
        p = q_s[4 * lane]     * v.x + q_s[4 * lane + 1] * v.y
          + q_s[4 * lane + 2] * v.z + q_s[4 * lane + 3] * v.w;
      }
    }
#pragma unroll
    for (int off = 32; off; off >>= 1) p += __shfl_down(p, off);
    if (lane == 0) e_arr[r] = p;
  }
  __syncthreads();
  // segment max
  float pm = -3.4e38f;
  for (int i = tid; i < n; i += 256) pm = fmaxf(pm, e_arr[i]);
#pragma unroll
  for (int off = 32; off; off >>= 1) pm = fmaxf(pm, __shfl_down(pm, off));
  if (lane == 0) red[wave] = pm;
  __syncthreads();
  float m = fmaxf(fmaxf(red[0], red[1]), fmaxf(red[2], red[3]));
  // exp + denom
  float ps = 0.f;
  for (int i = tid; i < n; i += 256) {
    float ex = __expf(e_arr[i] - m);
    e_arr[i] = ex;
    ps += ex;
  }
#pragma unroll
  for (int off = 32; off; off >>= 1) ps += __shfl_down(ps, off);
  if (lane == 0) red[4 + wave] = ps;
  __syncthreads();
  float denom = red[4] + red[5] + red[6] + red[7];
  float inv = (denom > 0.f) ? 1.f / denom : 0.f;
  // r-pass: feature-parallel weighted sum
  if (tid < F_DIM) {
    float acc = 0.f;
    if (staged) {
      for (int i = 0; i < n; i++) acc += e_arr[i] * b2f(xs[i * F_DIM + tid]);
    } else {
      for (int i = 0; i < n; i++)
        acc += e_arr[i] * xf[(size_t)(start + i) * F_DIM + tid];
    }
    float rv = acc * inv;
    if (step < 2) {
      Arow[200 + tid] = f2bu(rv);
    } else {
      out[(size_t)b * 400 + tid]       = q_s[tid];
      out[(size_t)b * 400 + 200 + tid] = rv;
    }
  }
}

extern "C" void kernel_launch(void* const* d_in, const int* in_sizes, int n_in,
                              void* d_out, int out_size, void* d_ws, size_t ws_size,
                              hipStream_t stream) {
  const float* x    = (const float*)d_in[0];
  const int*   batch= (const int*)d_in[1];
  const float* cosc = (const float*)d_in[2];
  const float* qs0  = (const float*)d_in[3];
  const float* Wih  = (const float*)d_in[4];
  const float* Whh  = (const float*)d_in[5];
  const float* bih  = (const float*)d_in[6];
  const float* bhh  = (const float*)d_in[7];
  char* ws = (char*)d_ws;
  // ws layout (bytes, all 16B aligned), total ~64.7 MB:
  unsigned short* xb   = (unsigned short*)(ws);               // 131072*200*2 = 52,428,800
  unsigned short* A    = (unsigned short*)(ws + 52428800);    // 2048*608*2   =  2,490,368
  unsigned short* Wc   = (unsigned short*)(ws + 54919168);    // 832*608*2    =  1,011,712
  float*          gates= (float*)(ws + 55930880);             // 2048*800*4   =  6,553,600
  float*          cvec = (float*)(ws + 62484480);             // 2048*200*4   =  1,638,400
  float*          bsum = (float*)(ws + 64122880);             // 800*4        =      3,200
  int*            soff = (int*)(ws + 64126080);               // 2052*4       =      8,208
  float*          esc  = (float*)(ws + 64134288);             // 131072*4     =    524,288
  float*          outp = (float*)d_out;

  setup_kernel<<<2492, 256, 0, stream>>>(Wih, Whh, bih, bhh, batch, Wc, bsum, soff);
  init_kernel<<<B_SEG, 256, 0, stream>>>(x, soff, cosc, qs0, xb, A);
  for (int s = 0; s < 3; s++) {
    gemm_gates<<<dim3(32, 13), 256, 0, stream>>>(A, Wc, gates);
    attn_fused<<<B_SEG, 256, 0, stream>>>(x, xb, soff, gates, bsum, cvec, esc, A, outp, s);
  }
}

// Round 5
// 306.654 us; speedup vs baseline: 1.4710x; 1.1417x over previous
//
#include <hip/hip_runtime.h>
#include <hip/hip_bf16.h>

#define N_NODES 131072
#define B_SEG   2048
#define F_DIM   200
#define K_DIM   608      // 400 (q_star) + 200 (h) + 8 zero pad = 19*32
#define MAXSEG  128

typedef __attribute__((ext_vector_type(8))) short bf16x8;
typedef __attribute__((ext_vector_type(4))) float f32x4;

__device__ __forceinline__ float b2f(unsigned short u) {
  union { unsigned int i; float f; } v; v.i = ((unsigned int)u) << 16; return v.f;
}
__device__ __forceinline__ unsigned short f2bu(float f) {
  __hip_bfloat16 h = __float2bfloat16(f);
  return *reinterpret_cast<unsigned short*>(&h);
}
__device__ __forceinline__ float sigmoidf_(float x) { return 1.f / (1.f + __expf(-x)); }

// ---- setup: pack Wc[832][608] bf16 (zero-padded), seg offsets, bias sum ----
__global__ __launch_bounds__(256) void setup_kernel(
    const float* __restrict__ Wih, const float* __restrict__ Whh,
    const float* __restrict__ bih, const float* __restrict__ bhh,
    const int* __restrict__ batch, unsigned short* __restrict__ Wc,
    float* __restrict__ bsum, int* __restrict__ seg_off) {
  int bid = blockIdx.x, tid = threadIdx.x;
  if (bid < 1976) {                       // 832*608/256 == 1976 exactly
    int idx = bid * 256 + tid;
    int row = idx / K_DIM, k = idx - row * K_DIM;
    float v = 0.f;
    if (row < 800) {
      if (k < 400)      v = Wih[row * 400 + k];
      else if (k < 600) v = Whh[row * 200 + (k - 400)];
    }
    Wc[idx] = f2bu(v);
  } else if (bid < 1976 + 512) {          // 131072/256 == 512
    int i = (bid - 1976) * 256 + tid;
    int v  = batch[i];
    int pv = (i == 0) ? -1 : batch[i - 1];
    for (int b = pv + 1; b <= v; b++) seg_off[b] = i;
  } else {
    int idx = (bid - 2488) * 256 + tid;
    if (idx < 800) bsum[idx] = bih[idx] + bhh[idx];
    else if (idx == 800) {                // trailing (possibly empty) segments
      int last = batch[N_NODES - 1];
      for (int b = last + 1; b <= B_SEG; b++) seg_off[b] = N_NODES;
    }
  }
}

// ---- init v2: single pass over x; convert->xb, h0 = seg_sum(cos*x) in regs ----
__global__ __launch_bounds__(256) void init_kernel(
    const float* __restrict__ xf, const int* __restrict__ seg_off,
    const float* __restrict__ cosc, const float* __restrict__ qs0,
    unsigned short* __restrict__ xb, unsigned short* __restrict__ A) {
  __shared__ float rpart[4][F_DIM];
  int b = blockIdx.x, tid = threadIdx.x;
  int start = seg_off[b], end = seg_off[b + 1];
  int n = end - start;
  unsigned short* Arow = A + (size_t)b * K_DIM;
  int wave = tid >> 6, lane = tid & 63;
  float a0 = 0.f, a1 = 0.f, a2 = 0.f, a3 = 0.f;
  for (int r = wave; r < n; r += 4) {
    if (lane < 50) {
      float4 v = *(const float4*)(xf + (size_t)(start + r) * F_DIM + 4 * lane);
      ushort4 o; o.x = f2bu(v.x); o.y = f2bu(v.y); o.z = f2bu(v.z); o.w = f2bu(v.w);
      *(ushort4*)(xb + (size_t)(start + r) * F_DIM + 4 * lane) = o;
      float cv = cosc[start + r];
      a0 += cv * b2f(o.x); a1 += cv * b2f(o.y);
      a2 += cv * b2f(o.z); a3 += cv * b2f(o.w);
    }
  }
  if (lane < 50) {
    rpart[wave][4 * lane]     = a0;
    rpart[wave][4 * lane + 1] = a1;
    rpart[wave][4 * lane + 2] = a2;
    rpart[wave][4 * lane + 3] = a3;
  }
  for (int j = tid; j < 400; j += 256)
    Arow[j] = f2bu(qs0[(size_t)b * 400 + j]);
  if (tid < 8) Arow[600 + tid] = 0;
  __syncthreads();
  if (tid < F_DIM) {
    float acc = rpart[0][tid] + rpart[1][tid] + rpart[2][tid] + rpart[3][tid];
    Arow[400 + tid] = f2bu(acc);
  }
}

// ---- gates GEMM, barrier-free: gates[2048,800] = A[2048,608] x Wc^T ----
__global__ __launch_bounds__(256) void gemm_gates(
    const unsigned short* __restrict__ A, const unsigned short* __restrict__ W,
    float* __restrict__ gates) {
  int tid = threadIdx.x;
  int bm = blockIdx.x * 64, bn = blockIdx.y * 64;
  int wave = tid >> 6, lane = tid & 63;
  int quad = lane >> 4, col = lane & 15;
  f32x4 acc[4];
#pragma unroll
  for (int t = 0; t < 4; t++) acc[t] = (f32x4){0.f, 0.f, 0.f, 0.f};
  const unsigned short* Ap = A + (size_t)(bm + wave * 16 + col) * K_DIM + quad * 8;
  const unsigned short* Wp = W + (size_t)(bn + col) * K_DIM + quad * 8;
#pragma unroll
  for (int k0 = 0; k0 < K_DIM; k0 += 32) {
    bf16x8 af = *(const bf16x8*)(Ap + k0);
#pragma unroll
    for (int t = 0; t < 4; t++) {
      bf16x8 bfr = *(const bf16x8*)(Wp + (size_t)t * 16 * K_DIM + k0);
      acc[t] = __builtin_amdgcn_mfma_f32_16x16x32_bf16(af, bfr, acc[t], 0, 0, 0);
    }
  }
#pragma unroll
  for (int t = 0; t < 4; t++) {
    int gn = bn + t * 16 + col;
    if (gn < 800) {
#pragma unroll
      for (int r = 0; r < 4; r++) {
        int gm = bm + wave * 16 + quad * 4 + r;
        gates[(size_t)gm * 800 + gn] = acc[t][r];
      }
    }
  }
}

// ---- fused LSTM cell + per-segment attention (no x staging, reg r-pass) ----
__global__ __launch_bounds__(256) void attn_fused(
    const unsigned short* __restrict__ xb, const int* __restrict__ seg_off,
    const float* __restrict__ gates, const float* __restrict__ bsum,
    float* __restrict__ cvec, float* __restrict__ esc,
    unsigned short* __restrict__ A, float* __restrict__ out, int step) {
  __shared__ float e_s[MAXSEG];
  __shared__ float q_s[F_DIM];
  __shared__ float rpart[4][F_DIM];
  __shared__ float red[8];
  int b = blockIdx.x, tid = threadIdx.x;
  int start = seg_off[b], end = seg_off[b + 1];
  int n = end - start;
  bool small = (n <= MAXSEG);
  float* e_arr = small ? e_s : (esc + start);
  unsigned short* Arow = A + (size_t)b * K_DIM;
  // LSTM cell for this segment's 200 features
  if (tid < F_DIM) {
    int f = tid;
    const float* g = gates + (size_t)b * 800;
    float gi = g[f]       + bsum[f];
    float gf = g[200 + f] + bsum[200 + f];
    float gg = g[400 + f] + bsum[400 + f];
    float go = g[600 + f] + bsum[600 + f];
    float cp = (step > 0) ? cvec[(size_t)b * F_DIM + f] : 0.f;
    float cn = sigmoidf_(gf) * cp + sigmoidf_(gi) * tanhf(gg);
    float hn = sigmoidf_(go) * tanhf(cn);
    cvec[(size_t)b * F_DIM + f] = cn;
    q_s[f] = hn;
    if (step < 2) {
      unsigned short hb = f2bu(hn);
      Arow[f] = hb;                       // q part of next q_star
      Arow[400 + f] = hb;                 // hidden for next cell
    }
  }
  __syncthreads();
  int wave = tid >> 6, lane = tid & 63;
  // per-lane q fragment in registers
  float q0 = 0.f, q1 = 0.f, q2 = 0.f, q3 = 0.f;
  if (lane < 50) {
    q0 = q_s[4 * lane];     q1 = q_s[4 * lane + 1];
    q2 = q_s[4 * lane + 2]; q3 = q_s[4 * lane + 3];
  }
  const unsigned short* xrow = xb + (size_t)start * F_DIM + 4 * lane;
  // e-pass: one row per wave, lanes 0..49 cover 200 features x4
  for (int r = wave; r < n; r += 4) {
    float p = 0.f;
    if (lane < 50) {
      ushort4 v = *(const ushort4*)(xrow + (size_t)r * F_DIM);
      p = q0 * b2f(v.x) + q1 * b2f(v.y) + q2 * b2f(v.z) + q3 * b2f(v.w);
    }
#pragma unroll
    for (int off = 32; off; off >>= 1) p += __shfl_down(p, off);
    if (lane == 0) e_arr[r] = p;
  }
  __syncthreads();
  // segment max
  float pm = -3.4e38f;
  for (int i = tid; i < n; i += 256) pm = fmaxf(pm, e_arr[i]);
#pragma unroll
  for (int off = 32; off; off >>= 1) pm = fmaxf(pm, __shfl_down(pm, off));
  if (lane == 0) red[wave] = pm;
  __syncthreads();
  float m = fmaxf(fmaxf(red[0], red[1]), fmaxf(red[2], red[3]));
  // exp + denom
  float ps = 0.f;
  for (int i = tid; i < n; i += 256) {
    float ex = __expf(e_arr[i] - m);
    e_arr[i] = ex;
    ps += ex;
  }
#pragma unroll
  for (int off = 32; off; off >>= 1) ps += __shfl_down(ps, off);
  if (lane == 0) red[4 + wave] = ps;
  __syncthreads();
  float denom = red[4] + red[5] + red[6] + red[7];
  float inv = (denom > 0.f) ? 1.f / denom : 0.f;
  // r-pass: wave-parallel rows, register accumulators (x rows L2-hot)
  float a0 = 0.f, a1 = 0.f, a2 = 0.f, a3 = 0.f;
  for (int r = wave; r < n; r += 4) {
    float wv = e_arr[r];
    if (lane < 50) {
      ushort4 v = *(const ushort4*)(xrow + (size_t)r * F_DIM);
      a0 += wv * b2f(v.x); a1 += wv * b2f(v.y);
      a2 += wv * b2f(v.z); a3 += wv * b2f(v.w);
    }
  }
  if (lane < 50) {
    rpart[wave][4 * lane]     = a0;
    rpart[wave][4 * lane + 1] = a1;
    rpart[wave][4 * lane + 2] = a2;
    rpart[wave][4 * lane + 3] = a3;
  }
  __syncthreads();
  if (tid < F_DIM) {
    float rv = (rpart[0][tid] + rpart[1][tid] + rpart[2][tid] + rpart[3][tid]) * inv;
    if (step < 2) {
      Arow[200 + tid] = f2bu(rv);
    } else {
      out[(size_t)b * 400 + tid]       = q_s[tid];
      out[(size_t)b * 400 + 200 + tid] = rv;
    }
  }
}

extern "C" void kernel_launch(void* const* d_in, const int* in_sizes, int n_in,
                              void* d_out, int out_size, void* d_ws, size_t ws_size,
                              hipStream_t stream) {
  const float* x    = (const float*)d_in[0];
  const int*   batch= (const int*)d_in[1];
  const float* cosc = (const float*)d_in[2];
  const float* qs0  = (const float*)d_in[3];
  const float* Wih  = (const float*)d_in[4];
  const float* Whh  = (const float*)d_in[5];
  const float* bih  = (const float*)d_in[6];
  const float* bhh  = (const float*)d_in[7];
  char* ws = (char*)d_ws;
  // ws layout (bytes, all 16B aligned), total ~64.7 MB:
  unsigned short* xb   = (unsigned short*)(ws);               // 131072*200*2 = 52,428,800
  unsigned short* A    = (unsigned short*)(ws + 52428800);    // 2048*608*2   =  2,490,368
  unsigned short* Wc   = (unsigned short*)(ws + 54919168);    // 832*608*2    =  1,011,712
  float*          gates= (float*)(ws + 55930880);             // 2048*800*4   =  6,553,600
  float*          cvec = (float*)(ws + 62484480);             // 2048*200*4   =  1,638,400
  float*          bsum = (float*)(ws + 64122880);             // 800*4        =      3,200
  int*            soff = (int*)(ws + 64126080);               // 2052*4       =      8,208
  float*          esc  = (float*)(ws + 64134288);             // 131072*4     =    524,288
  float*          outp = (float*)d_out;

  setup_kernel<<<2492, 256, 0, stream>>>(Wih, Whh, bih, bhh, batch, Wc, bsum, soff);
  init_kernel<<<B_SEG, 256, 0, stream>>>(x, soff, cosc, qs0, xb, A);
  for (int s = 0; s < 3; s++) {
    gemm_gates<<<dim3(32, 13), 256, 0, stream>>>(A, Wc, gates);
    attn_fused<<<B_SEG, 256, 0, stream>>>(xb, soff, gates, bsum, cvec, esc, A, outp, s);
  }
}

// Round 6
// 287.870 us; speedup vs baseline: 1.5670x; 1.0653x over previous
//
#include <hip/hip_runtime.h>
#include <hip/hip_bf16.h>

#define N_NODES 131072
#define B_SEG   2048
#define F_DIM   200
#define K_DIM   608      // 400 (q_star) + 200 (h) + 8 zero pad = 19*32
#define NEG_INF (-3.4e38f)

typedef __attribute__((ext_vector_type(8))) short bf16x8;
typedef __attribute__((ext_vector_type(4))) float f32x4;

__device__ __forceinline__ float b2f(unsigned short u) {
  union { unsigned int i; float f; } v; v.i = ((unsigned int)u) << 16; return v.f;
}
__device__ __forceinline__ unsigned short f2bu(float f) {
  __hip_bfloat16 h = __float2bfloat16(f);
  return *reinterpret_cast<unsigned short*>(&h);
}
__device__ __forceinline__ float sigmoidf_(float x) { return 1.f / (1.f + __expf(-x)); }

// ---- setup: pack Wc[832][608] bf16 (zero-padded), seg offsets, bias sum ----
__global__ __launch_bounds__(256) void setup_kernel(
    const float* __restrict__ Wih, const float* __restrict__ Whh,
    const float* __restrict__ bih, const float* __restrict__ bhh,
    const int* __restrict__ batch, unsigned short* __restrict__ Wc,
    float* __restrict__ bsum, int* __restrict__ seg_off) {
  int bid = blockIdx.x, tid = threadIdx.x;
  if (bid < 1976) {                       // 832*608/256 == 1976 exactly
    int idx = bid * 256 + tid;
    int row = idx / K_DIM, k = idx - row * K_DIM;
    float v = 0.f;
    if (row < 800) {
      if (k < 400)      v = Wih[row * 400 + k];
      else if (k < 600) v = Whh[row * 200 + (k - 400)];
    }
    Wc[idx] = f2bu(v);
  } else if (bid < 1976 + 512) {          // 131072/256 == 512
    int i = (bid - 1976) * 256 + tid;
    int v  = batch[i];
    int pv = (i == 0) ? -1 : batch[i - 1];
    for (int b = pv + 1; b <= v; b++) seg_off[b] = i;
  } else {
    int idx = (bid - 2488) * 256 + tid;
    if (idx < 800) bsum[idx] = bih[idx] + bhh[idx];
    else if (idx == 800) {                // trailing (possibly empty) segments
      int last = batch[N_NODES - 1];
      for (int b = last + 1; b <= B_SEG; b++) seg_off[b] = N_NODES;
    }
  }
}

// ---- init: single pass over x; convert->xb, h0 = seg_sum(cos*x) in regs ----
__global__ __launch_bounds__(256) void init_kernel(
    const float* __restrict__ xf, const int* __restrict__ seg_off,
    const float* __restrict__ cosc, const float* __restrict__ qs0,
    unsigned short* __restrict__ xb, unsigned short* __restrict__ A) {
  __shared__ float rpart[4][F_DIM];
  int b = blockIdx.x, tid = threadIdx.x;
  int start = seg_off[b], end = seg_off[b + 1];
  int n = end - start;
  unsigned short* Arow = A + (size_t)b * K_DIM;
  int wave = tid >> 6, lane = tid & 63;
  float a0 = 0.f, a1 = 0.f, a2 = 0.f, a3 = 0.f;
  for (int r = wave; r < n; r += 4) {
    if (lane < 50) {
      float4 v = *(const float4*)(xf + (size_t)(start + r) * F_DIM + 4 * lane);
      ushort4 o; o.x = f2bu(v.x); o.y = f2bu(v.y); o.z = f2bu(v.z); o.w = f2bu(v.w);
      *(ushort4*)(xb + (size_t)(start + r) * F_DIM + 4 * lane) = o;
      float cv = cosc[start + r];
      a0 += cv * b2f(o.x); a1 += cv * b2f(o.y);
      a2 += cv * b2f(o.z); a3 += cv * b2f(o.w);
    }
  }
  if (lane < 50) {
    rpart[wave][4 * lane]     = a0;
    rpart[wave][4 * lane + 1] = a1;
    rpart[wave][4 * lane + 2] = a2;
    rpart[wave][4 * lane + 3] = a3;
  }
  for (int j = tid; j < 400; j += 256)
    Arow[j] = f2bu(qs0[(size_t)b * 400 + j]);
  if (tid < 8) Arow[600 + tid] = 0;
  __syncthreads();
  if (tid < F_DIM) {
    float acc = rpart[0][tid] + rpart[1][tid] + rpart[2][tid] + rpart[3][tid];
    Arow[400 + tid] = f2bu(acc);
  }
}

// ---- gates GEMM, barrier-free: gates[2048,800] = A[2048,608] x Wc^T ----
__global__ __launch_bounds__(256) void gemm_gates(
    const unsigned short* __restrict__ A, const unsigned short* __restrict__ W,
    float* __restrict__ gates) {
  int tid = threadIdx.x;
  int bm = blockIdx.x * 64, bn = blockIdx.y * 64;
  int wave = tid >> 6, lane = tid & 63;
  int quad = lane >> 4, col = lane & 15;
  f32x4 acc[4];
#pragma unroll
  for (int t = 0; t < 4; t++) acc[t] = (f32x4){0.f, 0.f, 0.f, 0.f};
  const unsigned short* Ap = A + (size_t)(bm + wave * 16 + col) * K_DIM + quad * 8;
  const unsigned short* Wp = W + (size_t)(bn + col) * K_DIM + quad * 8;
#pragma unroll
  for (int k0 = 0; k0 < K_DIM; k0 += 32) {
    bf16x8 af = *(const bf16x8*)(Ap + k0);
#pragma unroll
    for (int t = 0; t < 4; t++) {
      bf16x8 bfr = *(const bf16x8*)(Wp + (size_t)t * 16 * K_DIM + k0);
      acc[t] = __builtin_amdgcn_mfma_f32_16x16x32_bf16(af, bfr, acc[t], 0, 0, 0);
    }
  }
#pragma unroll
  for (int t = 0; t < 4; t++) {
    int gn = bn + t * 16 + col;
    if (gn < 800) {
#pragma unroll
      for (int r = 0; r < 4; r++) {
        int gm = bm + wave * 16 + quad * 4 + r;
        gates[(size_t)gm * 800 + gn] = acc[t][r];
      }
    }
  }
}

// ---- fused LSTM cell + online-softmax attention (single x pass) ----
__global__ __launch_bounds__(256) void attn_fused(
    const unsigned short* __restrict__ xb, const int* __restrict__ seg_off,
    const float* __restrict__ gates, const float* __restrict__ bsum,
    float* __restrict__ cvec, unsigned short* __restrict__ A,
    float* __restrict__ out, int step) {
  __shared__ float q_s[F_DIM];
  __shared__ float rpart[4][F_DIM];
  __shared__ float red[8];
  int b = blockIdx.x, tid = threadIdx.x;
  int start = seg_off[b], end = seg_off[b + 1];
  int n = end - start;
  unsigned short* Arow = A + (size_t)b * K_DIM;
  // LSTM cell for this segment's 200 features
  if (tid < F_DIM) {
    int f = tid;
    const float* g = gates + (size_t)b * 800;
    float gi = g[f]       + bsum[f];
    float gf = g[200 + f] + bsum[200 + f];
    float gg = g[400 + f] + bsum[400 + f];
    float go = g[600 + f] + bsum[600 + f];
    float cp = (step > 0) ? cvec[(size_t)b * F_DIM + f] : 0.f;
    float cn = sigmoidf_(gf) * cp + sigmoidf_(gi) * tanhf(gg);
    float hn = sigmoidf_(go) * tanhf(cn);
    cvec[(size_t)b * F_DIM + f] = cn;
    q_s[f] = hn;
    if (step < 2) {
      unsigned short hb = f2bu(hn);
      Arow[f] = hb;                       // q part of next q_star
      Arow[400 + f] = hb;                 // hidden for next cell
    }
  }
  __syncthreads();
  int wave = tid >> 6, lane = tid & 63;
  // per-lane q fragment in registers
  float q0 = 0.f, q1 = 0.f, q2 = 0.f, q3 = 0.f;
  if (lane < 50) {
    q0 = q_s[4 * lane];     q1 = q_s[4 * lane + 1];
    q2 = q_s[4 * lane + 2]; q3 = q_s[4 * lane + 3];
  }
  const unsigned short* xrow = xb + (size_t)start * F_DIM + 4 * lane;
  // online softmax: single pass over rows, x read once
  float m = NEG_INF, l = 0.f;
  float a0 = 0.f, a1 = 0.f, a2 = 0.f, a3 = 0.f;
  for (int r = wave; r < n; r += 4) {
    float x0 = 0.f, x1 = 0.f, x2 = 0.f, x3 = 0.f;
    float p = 0.f;
    if (lane < 50) {
      ushort4 v = *(const ushort4*)(xrow + (size_t)r * F_DIM);
      x0 = b2f(v.x); x1 = b2f(v.y); x2 = b2f(v.z); x3 = b2f(v.w);
      p = q0 * x0 + q1 * x1 + q2 * x2 + q3 * x3;
    }
#pragma unroll
    for (int off = 32; off; off >>= 1) p += __shfl_down(p, off);
    float e = __shfl(p, 0);               // broadcast row score to all lanes
    float mn = fmaxf(m, e);
    float fac = __expf(m - mn);           // first iter: exp(-inf)=0
    float w  = __expf(e - mn);
    l  = l * fac + w;
    a0 = a0 * fac + w * x0;  a1 = a1 * fac + w * x1;
    a2 = a2 * fac + w * x2;  a3 = a3 * fac + w * x3;
    m = mn;
  }
  // cross-wave combine: (m,l,a) triples
  if (lane == 0) red[wave] = m;
  __syncthreads();
  float M = fmaxf(fmaxf(red[0], red[1]), fmaxf(red[2], red[3]));
  float facw = (m > NEG_INF) ? __expf(m - M) : 0.f;
  if (lane == 0) red[4 + wave] = l * facw;
  if (lane < 50) {
    rpart[wave][4 * lane]     = a0 * facw;
    rpart[wave][4 * lane + 1] = a1 * facw;
    rpart[wave][4 * lane + 2] = a2 * facw;
    rpart[wave][4 * lane + 3] = a3 * facw;
  }
  __syncthreads();
  float L = red[4] + red[5] + red[6] + red[7];
  float inv = (L > 0.f) ? 1.f / L : 0.f;
  if (tid < F_DIM) {
    float rv = (rpart[0][tid] + rpart[1][tid] + rpart[2][tid] + rpart[3][tid]) * inv;
    if (step < 2) {
      Arow[200 + tid] = f2bu(rv);
    } else {
      out[(size_t)b * 400 + tid]       = q_s[tid];
      out[(size_t)b * 400 + 200 + tid] = rv;
    }
  }
}

extern "C" void kernel_launch(void* const* d_in, const int* in_sizes, int n_in,
                              void* d_out, int out_size, void* d_ws, size_t ws_size,
                              hipStream_t stream) {
  const float* x    = (const float*)d_in[0];
  const int*   batch= (const int*)d_in[1];
  const float* cosc = (const float*)d_in[2];
  const float* qs0  = (const float*)d_in[3];
  const float* Wih  = (const float*)d_in[4];
  const float* Whh  = (const float*)d_in[5];
  const float* bih  = (const float*)d_in[6];
  const float* bhh  = (const float*)d_in[7];
  char* ws = (char*)d_ws;
  // ws layout (bytes, all 16B aligned), total ~64.2 MB:
  unsigned short* xb   = (unsigned short*)(ws);               // 131072*200*2 = 52,428,800
  unsigned short* A    = (unsigned short*)(ws + 52428800);    // 2048*608*2   =  2,490,368
  unsigned short* Wc   = (unsigned short*)(ws + 54919168);    // 832*608*2    =  1,011,712
  float*          gates= (float*)(ws + 55930880);             // 2048*800*4   =  6,553,600
  float*          cvec = (float*)(ws + 62484480);             // 2048*200*4   =  1,638,400
  float*          bsum = (float*)(ws + 64122880);             // 800*4        =      3,200
  int*            soff = (int*)(ws + 64126080);               // 2052*4       =      8,208
  float*          outp = (float*)d_out;

  setup_kernel<<<2492, 256, 0, stream>>>(Wih, Whh, bih, bhh, batch, Wc, bsum, soff);
  init_kernel<<<B_SEG, 256, 0, stream>>>(x, soff, cosc, qs0, xb, A);
  for (int s = 0; s < 3; s++) {
    gemm_gates<<<dim3(32, 13), 256, 0, stream>>>(A, Wc, gates);
    attn_fused<<<B_SEG, 256, 0, stream>>>(xb, soff, gates, bsum, cvec, A, outp, s);
  }
}

// Round 7
// 275.447 us; speedup vs baseline: 1.6376x; 1.0451x over previous
//
#include <hip/hip_runtime.h>
#include <hip/hip_bf16.h>

#define N_NODES 131072
#define B_SEG   2048
#define F_DIM   200
#define K_DIM   608      // 400 (q_star) + 200 (h) + 8 zero pad = 19*32
#define NEG_INF (-3.4e38f)

typedef __attribute__((ext_vector_type(8))) short bf16x8;
typedef __attribute__((ext_vector_type(4))) float f32x4;

__device__ __forceinline__ float b2f(unsigned short u) {
  union { unsigned int i; float f; } v; v.i = ((unsigned int)u) << 16; return v.f;
}
__device__ __forceinline__ unsigned short f2bu(float f) {
  __hip_bfloat16 h = __float2bfloat16(f);
  return *reinterpret_cast<unsigned short*>(&h);
}
__device__ __forceinline__ float sigmoidf_(float x) { return 1.f / (1.f + __expf(-x)); }

// ---- setup: pack Wc[832][608] bf16 (zero-padded), seg offsets, bias sum ----
__global__ __launch_bounds__(256) void setup_kernel(
    const float* __restrict__ Wih, const float* __restrict__ Whh,
    const float* __restrict__ bih, const float* __restrict__ bhh,
    const int* __restrict__ batch, unsigned short* __restrict__ Wc,
    float* __restrict__ bsum, int* __restrict__ seg_off) {
  int bid = blockIdx.x, tid = threadIdx.x;
  if (bid < 1976) {                       // 832*608/256 == 1976 exactly
    int idx = bid * 256 + tid;
    int row = idx / K_DIM, k = idx - row * K_DIM;
    float v = 0.f;
    if (row < 800) {
      if (k < 400)      v = Wih[row * 400 + k];
      else if (k < 600) v = Whh[row * 200 + (k - 400)];
    }
    Wc[idx] = f2bu(v);
  } else if (bid < 1976 + 512) {          // 131072/256 == 512
    int i = (bid - 1976) * 256 + tid;
    int v  = batch[i];
    int pv = (i == 0) ? -1 : batch[i - 1];
    for (int b = pv + 1; b <= v; b++) seg_off[b] = i;
  } else {
    int idx = (bid - 2488) * 256 + tid;
    if (idx < 800) bsum[idx] = bih[idx] + bhh[idx];
    else if (idx == 800) {                // trailing (possibly empty) segments
      int last = batch[N_NODES - 1];
      for (int b = last + 1; b <= B_SEG; b++) seg_off[b] = N_NODES;
    }
  }
}

// ---- init v3: thread=(rowgroup,col4); full-lane coalesced single x pass ----
__global__ __launch_bounds__(256) void init_kernel(
    const float* __restrict__ xf, const int* __restrict__ seg_off,
    const float* __restrict__ cosc, const float* __restrict__ qs0,
    unsigned short* __restrict__ xb, unsigned short* __restrict__ A) {
  __shared__ float rpart[5][F_DIM];
  int b = blockIdx.x, tid = threadIdx.x;
  int start = seg_off[b], end = seg_off[b + 1];
  int n = end - start;
  unsigned short* Arow = A + (size_t)b * K_DIM;
  int rgrp = tid / 50, col4 = tid - rgrp * 50;   // rgrp 0..4 active, col4 0..49
  float a0 = 0.f, a1 = 0.f, a2 = 0.f, a3 = 0.f;
  if (rgrp < 5) {
    for (int r = rgrp; r < n; r += 5) {
      float4 v = *(const float4*)(xf + (size_t)(start + r) * F_DIM + 4 * col4);
      ushort4 o; o.x = f2bu(v.x); o.y = f2bu(v.y); o.z = f2bu(v.z); o.w = f2bu(v.w);
      *(ushort4*)(xb + (size_t)(start + r) * F_DIM + 4 * col4) = o;
      float cv = cosc[start + r];
      a0 += cv * b2f(o.x); a1 += cv * b2f(o.y);
      a2 += cv * b2f(o.z); a3 += cv * b2f(o.w);
    }
    rpart[rgrp][4 * col4]     = a0;
    rpart[rgrp][4 * col4 + 1] = a1;
    rpart[rgrp][4 * col4 + 2] = a2;
    rpart[rgrp][4 * col4 + 3] = a3;
  }
  if (tid < 100) {                         // qs0 row: 400 f32 -> 400 bf16
    float4 v = *(const float4*)(qs0 + (size_t)b * 400 + 4 * tid);
    ushort4 o; o.x = f2bu(v.x); o.y = f2bu(v.y); o.z = f2bu(v.z); o.w = f2bu(v.w);
    *(ushort4*)(Arow + 4 * tid) = o;
  }
  if (tid < 8) Arow[600 + tid] = 0;
  __syncthreads();
  if (tid < F_DIM) {
    float acc = rpart[0][tid] + rpart[1][tid] + rpart[2][tid] + rpart[3][tid]
              + rpart[4][tid];
    Arow[400 + tid] = f2bu(acc);
  }
}

// ---- gates GEMM, barrier-free, BM=32/BN=64: 832 blocks ----
__global__ __launch_bounds__(256) void gemm_gates(
    const unsigned short* __restrict__ A, const unsigned short* __restrict__ W,
    float* __restrict__ gates) {
  int tid = threadIdx.x;
  int bm = blockIdx.x * 32, bn = blockIdx.y * 64;
  int wave = tid >> 6, lane = tid & 63;
  int quad = lane >> 4, col = lane & 15;
  int strip = wave >> 1;                  // 0..1 : 16-row strip
  int tp = (wave & 1) * 2;                // 0 or 2 : N-tile pair
  f32x4 acc[2];
  acc[0] = (f32x4){0.f, 0.f, 0.f, 0.f};
  acc[1] = (f32x4){0.f, 0.f, 0.f, 0.f};
  const unsigned short* Ap = A + (size_t)(bm + strip * 16 + col) * K_DIM + quad * 8;
  const unsigned short* Wp = W + (size_t)(bn + col) * K_DIM + quad * 8;
#pragma unroll
  for (int k0 = 0; k0 < K_DIM; k0 += 32) {
    bf16x8 af = *(const bf16x8*)(Ap + k0);
#pragma unroll
    for (int t = 0; t < 2; t++) {
      bf16x8 bfr = *(const bf16x8*)(Wp + (size_t)(tp + t) * 16 * K_DIM + k0);
      acc[t] = __builtin_amdgcn_mfma_f32_16x16x32_bf16(af, bfr, acc[t], 0, 0, 0);
    }
  }
#pragma unroll
  for (int t = 0; t < 2; t++) {
    int gn = bn + (tp + t) * 16 + col;
    if (gn < 800) {
#pragma unroll
      for (int r = 0; r < 4; r++) {
        int gm = bm + strip * 16 + quad * 4 + r;
        gates[(size_t)gm * 800 + gn] = acc[t][r];
      }
    }
  }
}

// ---- fused LSTM cell + online-softmax attention, half-wave per row ----
__global__ __launch_bounds__(256) void attn_fused(
    const unsigned short* __restrict__ xb, const int* __restrict__ seg_off,
    const float* __restrict__ gates, const float* __restrict__ bsum,
    float* __restrict__ cvec, unsigned short* __restrict__ A,
    float* __restrict__ out, int step) {
  __shared__ float q_s[F_DIM];
  __shared__ float rpart[8][F_DIM];
  __shared__ float redm[8], redl[8];
  int b = blockIdx.x, tid = threadIdx.x;
  int start = seg_off[b], end = seg_off[b + 1];
  int n = end - start;
  unsigned short* Arow = A + (size_t)b * K_DIM;
  // LSTM cell for this segment's 200 features
  if (tid < F_DIM) {
    int f = tid;
    const float* g = gates + (size_t)b * 800;
    float gi = g[f]       + bsum[f];
    float gf = g[200 + f] + bsum[200 + f];
    float gg = g[400 + f] + bsum[400 + f];
    float go = g[600 + f] + bsum[600 + f];
    float cp = (step > 0) ? cvec[(size_t)b * F_DIM + f] : 0.f;
    float cn = sigmoidf_(gf) * cp + sigmoidf_(gi) * tanhf(gg);
    float hn = sigmoidf_(go) * tanhf(cn);
    cvec[(size_t)b * F_DIM + f] = cn;
    q_s[f] = hn;
    if (step < 2) {
      unsigned short hb = f2bu(hn);
      Arow[f] = hb;                       // q part of next q_star
      Arow[400 + f] = hb;                 // hidden for next cell
    }
  }
  __syncthreads();
  int wave = tid >> 6, lane = tid & 63;
  int half = lane >> 5, hl = lane & 31;   // 32-lane half-wave
  int hw = wave * 2 + half;               // 0..7 : row owner
  bool act = (hl < 25);                   // 25 lanes x 8 elems = 200 features
  float q0=0,q1=0,q2=0,q3=0,q4=0,q5=0,q6=0,q7=0;
  if (act) {
    q0 = q_s[8*hl];   q1 = q_s[8*hl+1]; q2 = q_s[8*hl+2]; q3 = q_s[8*hl+3];
    q4 = q_s[8*hl+4]; q5 = q_s[8*hl+5]; q6 = q_s[8*hl+6]; q7 = q_s[8*hl+7];
  }
  const unsigned short* xp = xb + (size_t)start * F_DIM + 8 * hl;
  // online softmax: single pass, 2 rows per wave per iteration
  float m = NEG_INF, l = 0.f;
  float a0=0,a1=0,a2=0,a3=0,a4=0,a5=0,a6=0,a7=0;
  for (int r = hw; r < n; r += 8) {
    float x0=0,x1=0,x2=0,x3=0,x4=0,x5=0,x6=0,x7=0;
    float p = 0.f;
    if (act) {
      uint4 v = *(const uint4*)(xp + (size_t)r * F_DIM);
      x0 = b2f((unsigned short)(v.x & 0xffff)); x1 = b2f((unsigned short)(v.x >> 16));
      x2 = b2f((unsigned short)(v.y & 0xffff)); x3 = b2f((unsigned short)(v.y >> 16));
      x4 = b2f((unsigned short)(v.z & 0xffff)); x5 = b2f((unsigned short)(v.z >> 16));
      x6 = b2f((unsigned short)(v.w & 0xffff)); x7 = b2f((unsigned short)(v.w >> 16));
      p = q0*x0 + q1*x1 + q2*x2 + q3*x3 + q4*x4 + q5*x5 + q6*x6 + q7*x7;
    }
    // in-segment butterfly over the 32-lane half: every lane gets the row dot
#pragma unroll
    for (int off = 16; off; off >>= 1) p += __shfl_xor(p, off, 32);
    float e = p;
    float mn = fmaxf(m, e);
    float fac = __expf(m - mn);           // first iter: exp(-inf)=0
    float w  = __expf(e - mn);
    l  = l * fac + w;
    a0 = a0*fac + w*x0; a1 = a1*fac + w*x1; a2 = a2*fac + w*x2; a3 = a3*fac + w*x3;
    a4 = a4*fac + w*x4; a5 = a5*fac + w*x5; a6 = a6*fac + w*x6; a7 = a7*fac + w*x7;
    m = mn;
  }
  // cross-half-wave combine: 8 (m,l,a) triples
  if (hl == 0) redm[hw] = m;
  __syncthreads();
  float M = fmaxf(fmaxf(fmaxf(redm[0], redm[1]), fmaxf(redm[2], redm[3])),
                  fmaxf(fmaxf(redm[4], redm[5]), fmaxf(redm[6], redm[7])));
  float facw = (m > NEG_INF) ? __expf(m - M) : 0.f;
  if (hl == 0) redl[hw] = l * facw;
  if (act) {
    float* rp = &rpart[hw][8 * hl];
    rp[0] = a0*facw; rp[1] = a1*facw; rp[2] = a2*facw; rp[3] = a3*facw;
    rp[4] = a4*facw; rp[5] = a5*facw; rp[6] = a6*facw; rp[7] = a7*facw;
  }
  __syncthreads();
  float L = redl[0]+redl[1]+redl[2]+redl[3]+redl[4]+redl[5]+redl[6]+redl[7];
  float inv = (L > 0.f) ? 1.f / L : 0.f;
  if (tid < F_DIM) {
    float rv = (rpart[0][tid]+rpart[1][tid]+rpart[2][tid]+rpart[3][tid]
              + rpart[4][tid]+rpart[5][tid]+rpart[6][tid]+rpart[7][tid]) * inv;
    if (step < 2) {
      Arow[200 + tid] = f2bu(rv);
    } else {
      out[(size_t)b * 400 + tid]       = q_s[tid];
      out[(size_t)b * 400 + 200 + tid] = rv;
    }
  }
}

extern "C" void kernel_launch(void* const* d_in, const int* in_sizes, int n_in,
                              void* d_out, int out_size, void* d_ws, size_t ws_size,
                              hipStream_t stream) {
  const float* x    = (const float*)d_in[0];
  const int*   batch= (const int*)d_in[1];
  const float* cosc = (const float*)d_in[2];
  const float* qs0  = (const float*)d_in[3];
  const float* Wih  = (const float*)d_in[4];
  const float* Whh  = (const float*)d_in[5];
  const float* bih  = (const float*)d_in[6];
  const float* bhh  = (const float*)d_in[7];
  char* ws = (char*)d_ws;
  // ws layout (bytes, all 16B aligned), total ~64.2 MB:
  unsigned short* xb   = (unsigned short*)(ws);               // 131072*200*2 = 52,428,800
  unsigned short* A    = (unsigned short*)(ws + 52428800);    // 2048*608*2   =  2,490,368
  unsigned short* Wc   = (unsigned short*)(ws + 54919168);    // 832*608*2    =  1,011,712
  float*          gates= (float*)(ws + 55930880);             // 2048*800*4   =  6,553,600
  float*          cvec = (float*)(ws + 62484480);             // 2048*200*4   =  1,638,400
  float*          bsum = (float*)(ws + 64122880);             // 800*4        =      3,200
  int*            soff = (int*)(ws + 64126080);               // 2052*4       =      8,208
  float*          outp = (float*)d_out;

  setup_kernel<<<2492, 256, 0, stream>>>(Wih, Whh, bih, bhh, batch, Wc, bsum, soff);
  init_kernel<<<B_SEG, 256, 0, stream>>>(x, soff, cosc, qs0, xb, A);
  for (int s = 0; s < 3; s++) {
    gemm_gates<<<dim3(64, 13), 256, 0, stream>>>(A, Wc, gates);
    attn_fused<<<B_SEG, 256, 0, stream>>>(xb, soff, gates, bsum, cvec, A, outp, s);
  }
}